// Round 8
// baseline (175.174 us; speedup 1.0000x reference)
//
#include <hip/hip_runtime.h>
#include <hip/hip_bf16.h>

#define AS1 __attribute__((address_space(1)))
#define AS3 __attribute__((address_space(3)))

typedef __bf16 bf16_8 __attribute__((ext_vector_type(8)));
typedef float f32x4 __attribute__((ext_vector_type(4)));

constexpr int Tn = 4096;    // B*S tokens
constexpr int Hn = 1024;    // hidden
constexpr int Dn = 1024;    // expert inner dim
constexpr int En = 8;       // experts
constexpr int Pmax = 10240; // max padded gathered rows (8192 + 8*256)
constexpr int MaxT256 = 40; // max 256-row tiles
constexpr int MaxT128 = 80; // max 128-row tiles
constexpr float kAlpha = 1.702f;
constexpr float kLimit = 7.0f;

// f32 -> bf16 round-to-nearest-even
__device__ __forceinline__ unsigned short f2bf(float x) {
  unsigned u = __builtin_bit_cast(unsigned, x);
  u = u + 0x7FFFu + ((u >> 16) & 1u);
  return (unsigned short)(u >> 16);
}
__device__ __forceinline__ unsigned pack2(float a, float b) {
  return (unsigned)f2bf(a) | ((unsigned)f2bf(b) << 16);
}
__device__ __forceinline__ float bflo(unsigned v) { return __builtin_bit_cast(float, v << 16); }
__device__ __forceinline__ float bfhi(unsigned v) { return __builtin_bit_cast(float, v & 0xFFFF0000u); }

// async global->LDS, 16B per lane. lds ptr wave-uniform; HW adds lane*16.
__device__ __forceinline__ void gload_lds16(const void* gp, void* lp) {
  __builtin_amdgcn_global_load_lds(
      (const AS1 unsigned int*)(unsigned long long)gp,
      (AS3 unsigned int*)(unsigned int)(unsigned long long)lp,
      16, 0, 0);
}

// ================= pre-pass: route + X cvt + gate_up transpose + down transpose =================
constexpr int NB_CVT = 4096, NB_TGU = 4096, NB_TDN = 4096;

__global__ void k_prepass(const float* __restrict__ hs, const int* __restrict__ ridx,
                          const float* __restrict__ gup, const float* __restrict__ dwn,
                          unsigned short* __restrict__ xb,
                          unsigned short* __restrict__ wg, unsigned short* __restrict__ wu,
                          unsigned short* __restrict__ wdt,
                          int* __restrict__ tix, int* __restrict__ pos,
                          int* __restrict__ tileE, int* __restrict__ tileP0,
                          int* __restrict__ tileE2, int* __restrict__ tileP02,
                          int* __restrict__ ntiles, int* __restrict__ ntiles2) {
  __shared__ __align__(16) char smem[2 * 32 * 65 * 4 + 64];
  const int tid = threadIdx.x;
  int b = blockIdx.x;

  if (b == 0) {  // ---- routing: stable per-expert compaction, 256-padded ----
    int (*lh)[8] = (int(*)[8])smem;
    int* eoff = (int*)(smem + 8192);
#pragma unroll
    for (int e = 0; e < 8; e++) lh[tid][e] = 0;
    int myE[32];
#pragma unroll
    for (int s = 0; s < 32; s++) {
      int e = ridx[tid * 32 + s];
      myE[s] = e;
      lh[tid][e]++;
    }
    __syncthreads();
    if (tid < 8) {
      int tot = 0;
#pragma unroll 1
      for (int t = 0; t < 256; t++) { int v = lh[t][tid]; lh[t][tid] = tot; tot += v; }
      eoff[tid] = tot;
    }
    __syncthreads();
    if (tid == 0) {
      int off = 0, nt = 0, nt2 = 0;
#pragma unroll 1
      for (int e = 0; e < 8; e++) {
        int cnt = eoff[e];
        eoff[e] = off;
        int ntT = (cnt + 255) >> 8;
        for (int k = 0; k < ntT; k++) {
          tileE[nt] = e; tileP0[nt] = off + k * 256; nt++;
          tileE2[nt2] = e; tileP02[nt2] = off + k * 256; nt2++;
          tileE2[nt2] = e; tileP02[nt2] = off + k * 256 + 128; nt2++;
        }
        off += ntT * 256;
      }
      *ntiles = nt;
      *ntiles2 = nt2;
    }
    __syncthreads();
    for (int p = tid; p < Pmax; p += 256) tix[p] = 0;
    __syncthreads();
#pragma unroll
    for (int s = 0; s < 32; s++) {
      int slot = tid * 32 + s;
      int e = myE[s];
      int p = eoff[e] + (lh[tid][e]++);
      pos[slot] = p;
      tix[p] = slot >> 1;
    }
    return;
  }
  b -= 1;

  if (b < NB_CVT) {  // ---- X cvt ----
    int i = b * 256 + tid;
    float4 v = reinterpret_cast<const float4*>(hs)[i];
    ushort4 o;
    o.x = f2bf(v.x); o.y = f2bf(v.y); o.z = f2bf(v.z); o.w = f2bf(v.w);
    reinterpret_cast<ushort4*>(xb)[i] = o;
    return;
  }
  b -= NB_CVT;

  if (b < NB_TGU) {  // ---- gate_up transpose+deinterleave: 64h x 32d tile ----
    float (*lg)[65] = (float(*)[65])smem;
    float (*lu)[65] = (float(*)[65])(smem + 32 * 65 * 4);
    const int d0 = (b & 31) * 32, h0 = ((b >> 5) & 15) * 64, e = b >> 9;
    {
      const int hrow = tid >> 2, q = tid & 3;
      const float* src = gup + ((size_t)e * Hn + h0 + hrow) * (2 * Dn) + d0 * 2 + q * 16;
#pragma unroll
      for (int j = 0; j < 4; j++) {
        float4 v = *reinterpret_cast<const float4*>(src + j * 4);
        int dp = q * 8 + j * 2;
        lg[dp][hrow] = v.x; lu[dp][hrow] = v.y;
        lg[dp + 1][hrow] = v.z; lu[dp + 1][hrow] = v.w;
      }
    }
    __syncthreads();
    {
      const int d = tid >> 3, hc = (tid & 7) * 8;
      uint4 og, ou;
      og.x = pack2(lg[d][hc + 0], lg[d][hc + 1]); ou.x = pack2(lu[d][hc + 0], lu[d][hc + 1]);
      og.y = pack2(lg[d][hc + 2], lg[d][hc + 3]); ou.y = pack2(lu[d][hc + 2], lu[d][hc + 3]);
      og.z = pack2(lg[d][hc + 4], lg[d][hc + 5]); ou.z = pack2(lu[d][hc + 4], lu[d][hc + 5]);
      og.w = pack2(lg[d][hc + 6], lg[d][hc + 7]); ou.w = pack2(lu[d][hc + 6], lu[d][hc + 7]);
      *reinterpret_cast<uint4*>(wg + ((size_t)e * Dn + d0 + d) * Hn + h0 + hc) = og;
      *reinterpret_cast<uint4*>(wu + ((size_t)e * Dn + d0 + d) * Hn + h0 + hc) = ou;
    }
    return;
  }
  b -= NB_TGU;

  {  // ---- down_proj transpose: 64d x 32h tile ----
    float (*lt)[65] = (float(*)[65])smem;
    const int h0 = (b & 31) * 32, d0 = ((b >> 5) & 15) * 64, e = b >> 9;
    {
      const int drow = tid >> 2, q = tid & 3;
      const float* src = dwn + ((size_t)e * Dn + d0 + drow) * Hn + h0 + q * 8;
#pragma unroll
      for (int j = 0; j < 2; j++) {
        float4 v = *reinterpret_cast<const float4*>(src + j * 4);
        int hr = q * 8 + j * 4;
        lt[hr][drow] = v.x; lt[hr + 1][drow] = v.y; lt[hr + 2][drow] = v.z; lt[hr + 3][drow] = v.w;
      }
    }
    __syncthreads();
    {
      const int h = tid >> 3, dc = (tid & 7) * 8;
      uint4 o;
      o.x = pack2(lt[h][dc + 0], lt[h][dc + 1]);
      o.y = pack2(lt[h][dc + 2], lt[h][dc + 3]);
      o.z = pack2(lt[h][dc + 4], lt[h][dc + 5]);
      o.w = pack2(lt[h][dc + 6], lt[h][dc + 7]);
      *reinterpret_cast<uint4*>(wdt + ((size_t)e * Hn + h0 + h) * Dn + d0 + dc) = o;
    }
  }
}

// ================= GEMM1: 8-wave 256x128d 8-phase counted-vmcnt =================
// BM=256 gathered rows, 128 d-cols (G+U panels), BK=64, NSTEP=16.
// 8 waves: wr=wv>>2 (128-row half), wc=wv&3 (32 d-cols). Per wave: 8 M-frags x (2G+2U) x 2k.
// LDS 128KB: A[2][256*64], G[2][128*64], U[2][128*64] bf16, double-buffered.
// Staging quarters per K-tile: {A0, A1, G, U}, 2 loads/thread each, issued one per phase.
// Wait series vmcnt(4,6,6,8) -- never drains; raw s_barrier (no implicit vmcnt(0)).
__launch_bounds__(512, 1)
__global__ void k_gemm1(const unsigned short* __restrict__ xb,
                        const unsigned short* __restrict__ wg,
                        const unsigned short* __restrict__ wu,
                        const float* __restrict__ gub,
                        const int* __restrict__ tix,
                        const int* __restrict__ tileE,
                        const int* __restrict__ tileP0,
                        const int* __restrict__ ntiles,
                        unsigned short* __restrict__ midc) {
  __shared__ __align__(16) unsigned short As0[256 * 64], As1[256 * 64];
  __shared__ __align__(16) unsigned short Gs0[128 * 64], Gs1[128 * 64];
  __shared__ __align__(16) unsigned short Us0[128 * 64], Us1[128 * 64];

  const int nwg = gridDim.x;  // 320, %8==0
  const int orig = blockIdx.x;
  const int wgid = (orig & 7) * (nwg >> 3) + (orig >> 3);
  const int bx = wgid % MaxT256;
  const int by = wgid / MaxT256;
  if (bx >= *ntiles) return;
  const int e = tileE[bx];
  const int p0 = tileP0[bx];
  const int n0 = by * 128;

  const int tid = threadIdx.x;
  const int wv = tid >> 6, lane = tid & 63;
  const int wr = wv >> 2, wc = wv & 3;
  const int l8 = lane >> 3, c8 = lane & 7;
  const int fr = lane & 15, kg = lane >> 4;

  // tokens for this thread's 4 A-stage chunks (quarter q, load l)
  int tokc[2][2];
#pragma unroll
  for (int q = 0; q < 2; q++)
#pragma unroll
    for (int l = 0; l < 2; l++)
      tokc[q][l] = tix[p0 + q * 128 + (wv * 2 + l) * 8 + l8];

  const unsigned short* Gp = wg + ((size_t)e * Dn + n0) * Hn;
  const unsigned short* Up = wu + ((size_t)e * Dn + n0) * Hn;

  // stage helpers: each issues 2 gload_lds (wave-uniform dest, lane scatter = +lane*16B)
  auto stageA = [&](int q, unsigned short* dst, int k0) {
#pragma unroll
    for (int l = 0; l < 2; l++) {
      int rl = q * 128 + (wv * 2 + l) * 8;  // base row of this wave-load
      gload_lds16(xb + (size_t)tokc[q][l] * Hn + k0 + c8 * 8, (void*)(dst + rl * 64));
    }
  };
  auto stageB = [&](const unsigned short* src, unsigned short* dst, int k0) {
#pragma unroll
    for (int l = 0; l < 2; l++) {
      int rl = (wv * 2 + l) * 8;
      gload_lds16(src + (size_t)(rl + l8) * Hn + k0 + c8 * 8, (void*)(dst + rl * 64));
    }
  };

  f32x4 ag[8][2], au[8][2];
#pragma unroll
  for (int i = 0; i < 8; i++)
#pragma unroll
    for (int j = 0; j < 2; j++) { ag[i][j] = f32x4{0.f,0.f,0.f,0.f}; au[i][j] = f32x4{0.f,0.f,0.f,0.f}; }

  // prologue: stage tile 0 (A0, A1, G, U = 8 loads/thread)
  stageA(0, As0, 0);
  stageA(1, As0, 0);
  stageB(Gp, Gs0, 0);
  stageB(Up, Us0, 0);

  constexpr int NSTEP = 16;
  for (int t = 0; t < NSTEP; ++t) {
    const int cur = t & 1;
    unsigned short* Ac = cur ? As1 : As0;
    unsigned short* Gc = cur ? Gs1 : Gs0;
    unsigned short* Uc = cur ? Us1 : Us0;
    unsigned short* An = cur ? As0 : As1;
    unsigned short* Gn = cur ? Gs0 : Gs1;
    unsigned short* Un = cur ? Us0 : Us1;
    const int kn = ((t + 1) & (NSTEP - 1)) * 64;  // wrap stage on last iter (harmless)

    bf16_8 aK0[8], aK1[8], bg0[2], bg1[2], bu0[2], bu1[2];

    // ---- phase 0: stage A0(t+1); consume A k0 + G k0 ----
    stageA(0, An, kn);
    asm volatile("s_waitcnt vmcnt(4)" ::: "memory");
    __builtin_amdgcn_s_barrier();
#pragma unroll
    for (int i = 0; i < 8; i++)
      aK0[i] = *reinterpret_cast<const bf16_8*>(Ac + (wr * 128 + i * 16 + fr) * 64 + kg * 8);
#pragma unroll
    for (int j = 0; j < 2; j++)
      bg0[j] = *reinterpret_cast<const bf16_8*>(Gc + (wc * 32 + j * 16 + fr) * 64 + kg * 8);
    __builtin_amdgcn_s_setprio(1);
#pragma unroll
    for (int i = 0; i < 8; i++)
#pragma unroll
      for (int j = 0; j < 2; j++)
        ag[i][j] = __builtin_amdgcn_mfma_f32_16x16x32_bf16(aK0[i], bg0[j], ag[i][j], 0, 0, 0);
    __builtin_amdgcn_s_setprio(0);

    // ---- phase 1: stage A1(t+1); consume A k1 + G k1 ----
    stageA(1, An, kn);
    asm volatile("s_waitcnt vmcnt(6)" ::: "memory");
    __builtin_amdgcn_s_barrier();
#pragma unroll
    for (int i = 0; i < 8; i++)
      aK1[i] = *reinterpret_cast<const bf16_8*>(Ac + (wr * 128 + i * 16 + fr) * 64 + 32 + kg * 8);
#pragma unroll
    for (int j = 0; j < 2; j++)
      bg1[j] = *reinterpret_cast<const bf16_8*>(Gc + (wc * 32 + j * 16 + fr) * 64 + 32 + kg * 8);
    __builtin_amdgcn_s_setprio(1);
#pragma unroll
    for (int i = 0; i < 8; i++)
#pragma unroll
      for (int j = 0; j < 2; j++)
        ag[i][j] = __builtin_amdgcn_mfma_f32_16x16x32_bf16(aK1[i], bg1[j], ag[i][j], 0, 0, 0);
    __builtin_amdgcn_s_setprio(0);

    // ---- phase 2: stage G(t+1); consume U k0 (A k0 from regs) ----
    stageB(Gp, Gn, kn);
    asm volatile("s_waitcnt vmcnt(6)" ::: "memory");
    __builtin_amdgcn_s_barrier();
#pragma unroll
    for (int j = 0; j < 2; j++)
      bu0[j] = *reinterpret_cast<const bf16_8*>(Uc + (wc * 32 + j * 16 + fr) * 64 + kg * 8);
    __builtin_amdgcn_s_setprio(1);
#pragma unroll
    for (int i = 0; i < 8; i++)
#pragma unroll
      for (int j = 0; j < 2; j++)
        au[i][j] = __builtin_amdgcn_mfma_f32_16x16x32_bf16(aK0[i], bu0[j], au[i][j], 0, 0, 0);
    __builtin_amdgcn_s_setprio(0);

    // ---- phase 3: stage U(t+1); consume U k1 ----
    stageB(Up, Un, kn);
    asm volatile("s_waitcnt vmcnt(8)" ::: "memory");
    __builtin_amdgcn_s_barrier();
#pragma unroll
    for (int j = 0; j < 2; j++)
      bu1[j] = *reinterpret_cast<const bf16_8*>(Uc + (wc * 32 + j * 16 + fr) * 64 + 32 + kg * 8);
    __builtin_amdgcn_s_setprio(1);
#pragma unroll
    for (int i = 0; i < 8; i++)
#pragma unroll
      for (int j = 0; j < 2; j++)
        au[i][j] = __builtin_amdgcn_mfma_f32_16x16x32_bf16(aK1[i], bu1[j], au[i][j], 0, 0, 0);
    __builtin_amdgcn_s_setprio(0);

    // ---- iteration end: all reads of buf[cur] done before next iter stages into it ----
    asm volatile("s_waitcnt lgkmcnt(0)" ::: "memory");
    __builtin_amdgcn_s_barrier();
  }
  asm volatile("s_waitcnt vmcnt(0)" ::: "memory");

  // ---- epilogue: bias + clamped-GLU activation, store bf16 ----
  const int rg = kg;
  const float* gb = gub + e * 2 * Dn;
  const int dA = n0 + wc * 32 + fr, dB = dA + 16;
  const float gbiasA = gb[2 * dA], ubiasA = gb[2 * dA + 1];
  const float gbiasB = gb[2 * dB], ubiasB = gb[2 * dB + 1];
#pragma unroll
  for (int i = 0; i < 8; i++) {
#pragma unroll
    for (int r = 0; r < 4; r++) {
      int row = p0 + wr * 128 + i * 16 + rg * 4 + r;
#pragma unroll
      for (int j = 0; j < 2; j++) {
        int d = j ? dB : dA;
        float g = ag[i][j][r] + (j ? gbiasB : gbiasA);
        float u = au[i][j][r] + (j ? ubiasB : ubiasA);
        g = fminf(g, kLimit);
        u = fminf(fmaxf(u, -kLimit), kLimit);
        float sg = 1.0f / (1.0f + __expf(-kAlpha * g));
        float mid = (u + 1.0f) * g * sg;
        midc[(size_t)row * Dn + d] = f2bf(mid);
      }
    }
  }
}

// ================= GEMM2: ys[p][h] = midc[p][:] @ Wd_e (bf16 out) =================
// proven 2-phase form: BM=128, BN=64, BK=64; grid 80x16.
__launch_bounds__(256, 2)
__global__ void k_gemm2(const unsigned short* __restrict__ midc,
                        const unsigned short* __restrict__ wdt,
                        const int* __restrict__ tileE2,
                        const int* __restrict__ tileP02,
                        const int* __restrict__ ntiles2,
                        unsigned short* __restrict__ ys) {
  constexpr int BM = 128, BN = 64, BK = 64;
  __shared__ __align__(16) unsigned short As[BM * BK];
  __shared__ __align__(16) unsigned short Bs[BN * BK];
  const int nwg = gridDim.x * gridDim.y;
  const int orig = blockIdx.y * gridDim.x + blockIdx.x;
  const int wgid = (orig & 7) * (nwg >> 3) + (orig >> 3);
  const int bx = wgid % gridDim.x;
  const int by = wgid / gridDim.x;
  if (bx >= *ntiles2) return;
  const int e = tileE2[bx];
  const int p0 = tileP02[bx];
  const int n0 = by * BN;
  const int tid = threadIdx.x;
  const int wv = tid >> 6, lane = tid & 63;
  const int wr = wv >> 1, wc = wv & 1;
  const int r8 = lane >> 3, c8 = lane & 7;
  const unsigned short* Ap = midc + (size_t)p0 * Dn;
  const unsigned short* Bp = wdt + ((size_t)e * Hn + n0) * Dn;

  f32x4 acc[4][2];
#pragma unroll
  for (int i = 0; i < 4; i++)
#pragma unroll
    for (int j = 0; j < 2; j++) acc[i][j] = f32x4{0.f,0.f,0.f,0.f};

  for (int k0 = 0; k0 < Dn; k0 += BK) {
#pragma unroll
    for (int c = 0; c < 4; c++) {
      int ch = c * 4 + wv;
      gload_lds16(Ap + (size_t)(ch * 8 + r8) * Dn + k0 + c8 * 8, (void*)(As + ch * 512));
    }
#pragma unroll
    for (int c = 0; c < 2; c++) {
      int ch = c * 4 + wv;
      gload_lds16(Bp + (size_t)(ch * 8 + r8) * Dn + k0 + c8 * 8, (void*)(Bs + ch * 512));
    }
    asm volatile("s_waitcnt vmcnt(0)" ::: "memory");
    __syncthreads();
    const int fr = lane & 15, kg = lane >> 4;
#pragma unroll
    for (int kk = 0; kk < 2; kk++) {
      bf16_8 a[4], b[2];
#pragma unroll
      for (int i = 0; i < 4; i++)
        a[i] = *reinterpret_cast<const bf16_8*>(As + (wr * 64 + i * 16 + fr) * BK + kk * 32 + kg * 8);
#pragma unroll
      for (int j = 0; j < 2; j++)
        b[j] = *reinterpret_cast<const bf16_8*>(Bs + (wc * 32 + j * 16 + fr) * BK + kk * 32 + kg * 8);
#pragma unroll
      for (int i = 0; i < 4; i++)
#pragma unroll
        for (int j = 0; j < 2; j++)
          acc[i][j] = __builtin_amdgcn_mfma_f32_16x16x32_bf16(a[i], b[j], acc[i][j], 0, 0, 0);
    }
    __syncthreads();
  }

  const int fr = lane & 15, rg = lane >> 4;
#pragma unroll
  for (int i = 0; i < 4; i++)
#pragma unroll
    for (int r = 0; r < 4; r++) {
      int row = p0 + wr * 64 + i * 16 + rg * 4 + r;
#pragma unroll
      for (int j = 0; j < 2; j++) {
        int col = n0 + wc * 32 + j * 16 + fr;
        ys[(size_t)row * Hn + col] = f2bf(acc[i][j][r]);
      }
    }
}

// ---- combine: out[t][h] = sum_k rw[t,e_k] * (ys[p_k][h] + db[e_k][h]) ----
__global__ void k_combine(const unsigned short* __restrict__ ys, const int* __restrict__ ridx,
                          const float* __restrict__ rw, const int* __restrict__ pos,
                          const float* __restrict__ db, float* __restrict__ out) {
  int idx = blockIdx.x * blockDim.x + threadIdx.x;
  int t = idx >> 7, hc = (idx & 127) << 3;
  int e0 = ridx[2 * t], e1 = ridx[2 * t + 1];
  int p0 = pos[2 * t], p1 = pos[2 * t + 1];
  float w0 = rw[t * En + e0], w1 = rw[t * En + e1];
  uint4 ya = *reinterpret_cast<const uint4*>(ys + (size_t)p0 * Hn + hc);
  uint4 yb = *reinterpret_cast<const uint4*>(ys + (size_t)p1 * Hn + hc);
  float4 da0 = *reinterpret_cast<const float4*>(db + (size_t)e0 * Hn + hc);
  float4 da1 = *reinterpret_cast<const float4*>(db + (size_t)e0 * Hn + hc + 4);
  float4 db0 = *reinterpret_cast<const float4*>(db + (size_t)e1 * Hn + hc);
  float4 db1 = *reinterpret_cast<const float4*>(db + (size_t)e1 * Hn + hc + 4);
  float4 o0, o1;
  o0.x = w0 * (bflo(ya.x) + da0.x) + w1 * (bflo(yb.x) + db0.x);
  o0.y = w0 * (bfhi(ya.x) + da0.y) + w1 * (bfhi(yb.x) + db0.y);
  o0.z = w0 * (bflo(ya.y) + da0.z) + w1 * (bflo(yb.y) + db0.z);
  o0.w = w0 * (bfhi(ya.y) + da0.w) + w1 * (bfhi(yb.y) + db0.w);
  o1.x = w0 * (bflo(ya.z) + da1.x) + w1 * (bflo(yb.z) + db1.x);
  o1.y = w0 * (bfhi(ya.z) + da1.y) + w1 * (bfhi(yb.z) + db1.y);
  o1.z = w0 * (bflo(ya.w) + da1.z) + w1 * (bflo(yb.w) + db1.z);
  o1.w = w0 * (bfhi(ya.w) + da1.w) + w1 * (bfhi(yb.w) + db1.w);
  *reinterpret_cast<float4*>(out + (size_t)t * Hn + hc) = o0;
  *reinterpret_cast<float4*>(out + (size_t)t * Hn + hc + 4) = o1;
}

extern "C" void kernel_launch(void* const* d_in, const int* in_sizes, int n_in,
                              void* d_out, int out_size, void* d_ws, size_t ws_size,
                              hipStream_t stream) {
  (void)in_sizes; (void)n_in; (void)out_size; (void)ws_size;
  const float* hs  = (const float*)d_in[0];
  const int*   ri  = (const int*)d_in[1];
  const float* rw  = (const float*)d_in[2];
  const float* gup = (const float*)d_in[3];
  const float* gub = (const float*)d_in[4];
  const float* dwn = (const float*)d_in[5];
  const float* db  = (const float*)d_in[6];
  float* out = (float*)d_out;

  char* ws = (char*)d_ws;
  int* tix     = (int*)(ws);              // Pmax ints (40KB)
  int* pos     = (int*)(ws + 65536);      // Sn ints (32KB)
  int* tileE   = (int*)(ws + 131072);
  int* tileP0  = (int*)(ws + 131584);
  int* tileE2  = (int*)(ws + 132096);
  int* tileP02 = (int*)(ws + 132608);
  int* ntiles  = (int*)(ws + 133120);
  int* ntiles2 = (int*)(ws + 133124);
  unsigned short* xb   = (unsigned short*)(ws + 262144);                        // 8 MiB
  unsigned short* wg   = (unsigned short*)(ws + 262144 + 8388608);              // 16 MiB
  unsigned short* wu   = (unsigned short*)(ws + 262144 + 8388608 + 16777216);   // 16 MiB
  unsigned short* wdt  = (unsigned short*)(ws + 262144 + 8388608 + 2*16777216); // 16 MiB
  unsigned short* midc = (unsigned short*)(ws + 262144 + 8388608 + 3*16777216); // 20 MiB
  unsigned short* ys   = (unsigned short*)(ws + 262144 + 8388608 + 3*16777216 + (size_t)Pmax * Dn * 2); // 20 MiB

  k_prepass<<<dim3(1 + NB_CVT + NB_TGU + NB_TDN), dim3(256), 0, stream>>>(
      hs, ri, gup, dwn, xb, wg, wu, wdt, tix, pos, tileE, tileP0, tileE2, tileP02, ntiles, ntiles2);
  k_gemm1<<<dim3(MaxT256 * (Dn / 128)), dim3(512), 0, stream>>>(
      xb, wg, wu, gub, tix, tileE, tileP0, ntiles, midc);
  k_gemm2<<<dim3(MaxT128, Hn / 64), dim3(256), 0, stream>>>(
      midc, wdt, tileE2, tileP02, ntiles2, ys);
  k_combine<<<dim3(Tn * Hn / 8 / 256), dim3(256), 0, stream>>>(ys, ri, rw, pos, db, out);
}

// Round 9
// 131.111 us; speedup vs baseline: 1.3361x; 1.3361x over previous
//
#include <hip/hip_runtime.h>
#include <hip/hip_bf16.h>

#define AS1 __attribute__((address_space(1)))
#define AS3 __attribute__((address_space(3)))

typedef __bf16 bf16_8 __attribute__((ext_vector_type(8)));
typedef float f32x4 __attribute__((ext_vector_type(4)));

constexpr int Tn = 4096;    // B*S tokens
constexpr int Hn = 1024;    // hidden
constexpr int Dn = 1024;    // expert inner dim
constexpr int En = 8;       // experts
constexpr int Pmax = 10240; // max padded gathered rows (8192 + 8*256)
constexpr int MaxT256 = 40; // max 256-row tiles
constexpr float kAlpha = 1.702f;
constexpr float kLimit = 7.0f;

// f32 -> bf16 round-to-nearest-even
__device__ __forceinline__ unsigned short f2bf(float x) {
  unsigned u = __builtin_bit_cast(unsigned, x);
  u = u + 0x7FFFu + ((u >> 16) & 1u);
  return (unsigned short)(u >> 16);
}
__device__ __forceinline__ unsigned pack2(float a, float b) {
  return (unsigned)f2bf(a) | ((unsigned)f2bf(b) << 16);
}
__device__ __forceinline__ float bflo(unsigned v) { return __builtin_bit_cast(float, v << 16); }
__device__ __forceinline__ float bfhi(unsigned v) { return __builtin_bit_cast(float, v & 0xFFFF0000u); }

// async global->LDS, 16B per lane. lds ptr wave-uniform; HW adds lane*16.
__device__ __forceinline__ void gload_lds16(const void* gp, void* lp) {
  __builtin_amdgcn_global_load_lds(
      (const AS1 unsigned int*)(unsigned long long)gp,
      (AS3 unsigned int*)(unsigned int)(unsigned long long)lp,
      16, 0, 0);
}

// ================= pre-pass: route + X cvt + gate_up transpose =================
constexpr int NB_CVT = 4096, NB_TGU = 4096, NB_TDN = 4096;
constexpr int NG1 = MaxT256 * 32;  // 1280 gemm1 blocks

__global__ void k_prepass(const float* __restrict__ hs, const int* __restrict__ ridx,
                          const float* __restrict__ gup,
                          unsigned short* __restrict__ xb,
                          unsigned short* __restrict__ wg, unsigned short* __restrict__ wu,
                          int* __restrict__ tix, int* __restrict__ pos,
                          int* __restrict__ tileE, int* __restrict__ tileP0,
                          int* __restrict__ ntiles) {
  __shared__ __align__(16) char smem[2 * 32 * 65 * 4 + 64];
  const int tid = threadIdx.x;
  int b = blockIdx.x;

  if (b == 0) {  // ---- routing: stable per-expert compaction, 256-padded tiles ----
    int (*lh)[8] = (int(*)[8])smem;
    int* eoff = (int*)(smem + 8192);
#pragma unroll
    for (int e = 0; e < 8; e++) lh[tid][e] = 0;
    int myE[32];
#pragma unroll
    for (int s = 0; s < 32; s++) {
      int e = ridx[tid * 32 + s];
      myE[s] = e;
      lh[tid][e]++;
    }
    __syncthreads();
    if (tid < 8) {
      int tot = 0;
#pragma unroll 1
      for (int t = 0; t < 256; t++) { int v = lh[t][tid]; lh[t][tid] = tot; tot += v; }
      eoff[tid] = tot;
    }
    __syncthreads();
    if (tid == 0) {
      int off = 0, nt = 0;
#pragma unroll 1
      for (int e = 0; e < 8; e++) {
        int cnt = eoff[e];
        eoff[e] = off;
        int ntT = (cnt + 255) >> 8;
        for (int k = 0; k < ntT; k++) { tileE[nt] = e; tileP0[nt] = off + k * 256; nt++; }
        off += ntT * 256;
      }
      *ntiles = nt;
    }
    __syncthreads();
    for (int p = tid; p < Pmax; p += 256) tix[p] = 0;
    __syncthreads();
#pragma unroll
    for (int s = 0; s < 32; s++) {
      int slot = tid * 32 + s;
      int e = myE[s];
      int p = eoff[e] + (lh[tid][e]++);
      pos[slot] = p;
      tix[p] = slot >> 1;
    }
    return;
  }
  b -= 1;

  if (b < NB_CVT) {  // ---- X cvt ----
    int i = b * 256 + tid;
    float4 v = reinterpret_cast<const float4*>(hs)[i];
    ushort4 o;
    o.x = f2bf(v.x); o.y = f2bf(v.y); o.z = f2bf(v.z); o.w = f2bf(v.w);
    reinterpret_cast<ushort4*>(xb)[i] = o;
    return;
  }
  b -= NB_CVT;

  {  // ---- gate_up transpose+deinterleave: 64h x 32d tile ----
    float (*lg)[65] = (float(*)[65])smem;
    float (*lu)[65] = (float(*)[65])(smem + 32 * 65 * 4);
    const int d0 = (b & 31) * 32, h0 = ((b >> 5) & 15) * 64, e = b >> 9;
    {
      const int hrow = tid >> 2, q = tid & 3;
      const float* src = gup + ((size_t)e * Hn + h0 + hrow) * (2 * Dn) + d0 * 2 + q * 16;
#pragma unroll
      for (int j = 0; j < 4; j++) {
        float4 v = *reinterpret_cast<const float4*>(src + j * 4);
        int dp = q * 8 + j * 2;
        lg[dp][hrow] = v.x; lu[dp][hrow] = v.y;
        lg[dp + 1][hrow] = v.z; lu[dp + 1][hrow] = v.w;
      }
    }
    __syncthreads();
    {
      const int d = tid >> 3, hc = (tid & 7) * 8;
      uint4 og, ou;
      og.x = pack2(lg[d][hc + 0], lg[d][hc + 1]); ou.x = pack2(lu[d][hc + 0], lu[d][hc + 1]);
      og.y = pack2(lg[d][hc + 2], lg[d][hc + 3]); ou.y = pack2(lu[d][hc + 2], lu[d][hc + 3]);
      og.z = pack2(lg[d][hc + 4], lg[d][hc + 5]); ou.z = pack2(lu[d][hc + 4], lu[d][hc + 5]);
      og.w = pack2(lg[d][hc + 6], lg[d][hc + 7]); ou.w = pack2(lu[d][hc + 6], lu[d][hc + 7]);
      *reinterpret_cast<uint4*>(wg + ((size_t)e * Dn + d0 + d) * Hn + h0 + hc) = og;
      *reinterpret_cast<uint4*>(wu + ((size_t)e * Dn + d0 + d) * Hn + h0 + hc) = ou;
    }
  }
}

// ================= mega-launch: GEMM1+act  ||  down_proj transpose =================
// GEMM1: BM=256 gathered rows, B-tile = [32 gate-d rows ; 32 up-d rows] (one 32-wide
// d-range), BK=64. 4 waves (4M x 1N): per-wave 64 rows x 64 B-cols, acc[4][4]=64 f32.
// Fragments j=0,1 are gate, j=2,3 are up for the SAME d -> (g,u) lane-local pairing.
// Staged bytes per block-K-step: A 32KB + B 8KB for 2.1 MFLOP (m97-class ratio).
__launch_bounds__(256, 3)
__global__ void k_main1(const unsigned short* __restrict__ xb,
                        const unsigned short* __restrict__ wg,
                        const unsigned short* __restrict__ wu,
                        const float* __restrict__ gub,
                        const int* __restrict__ tix,
                        const int* __restrict__ tileE,
                        const int* __restrict__ tileP0,
                        const int* __restrict__ ntiles,
                        unsigned short* __restrict__ midc,
                        const float* __restrict__ dwn,
                        unsigned short* __restrict__ wdt) {
  __shared__ __align__(16) char smem[40960];  // 40 KiB
  const int tid = threadIdx.x;

  if ((int)blockIdx.x >= NG1) {  // ---- down_proj transpose: 64d x 32h tile ----
    int b = blockIdx.x - NG1;
    float (*lt)[65] = (float(*)[65])smem;
    const int h0 = (b & 31) * 32, d0 = ((b >> 5) & 15) * 64, e = b >> 9;
    {
      const int drow = tid >> 2, q = tid & 3;
      const float* src = dwn + ((size_t)e * Dn + d0 + drow) * Hn + h0 + q * 8;
#pragma unroll
      for (int j = 0; j < 2; j++) {
        float4 v = *reinterpret_cast<const float4*>(src + j * 4);
        int hr = q * 8 + j * 4;
        lt[hr][drow] = v.x; lt[hr + 1][drow] = v.y; lt[hr + 2][drow] = v.z; lt[hr + 3][drow] = v.w;
      }
    }
    __syncthreads();
    {
      const int h = tid >> 3, dc = (tid & 7) * 8;
      uint4 o;
      o.x = pack2(lt[h][dc + 0], lt[h][dc + 1]);
      o.y = pack2(lt[h][dc + 2], lt[h][dc + 3]);
      o.z = pack2(lt[h][dc + 4], lt[h][dc + 5]);
      o.w = pack2(lt[h][dc + 6], lt[h][dc + 7]);
      *reinterpret_cast<uint4*>(wdt + ((size_t)e * Hn + h0 + h) * Dn + d0 + dc) = o;
    }
    return;
  }

  // ---- GEMM1 ----
  unsigned short* Xs = (unsigned short*)smem;            // 32 KiB (256 x 64)
  unsigned short* Bs = (unsigned short*)(smem + 32768);  // 8 KiB  (64 x 64)
  // XCD swizzle; panel index fastest so one A-tile stays L2-resident across panels
  const int orig = blockIdx.x;
  const int wgid = (orig & 7) * (NG1 >> 3) + (orig >> 3);
  const int by = wgid & 31;        // d-panel [0,32)
  const int bx = wgid >> 5;        // M-tile  [0,40)
  if (bx >= *ntiles) return;
  const int e = tileE[bx];
  const int p0 = tileP0[bx];
  const int n0 = by * 32;
  const int wv = tid >> 6, lane = tid & 63;
  const int r8 = lane >> 3, c8 = lane & 7;
  const int fr = lane & 15, kg = lane >> 4;

  int tokc[8];
#pragma unroll
  for (int c = 0; c < 8; c++) tokc[c] = tix[p0 + (c * 4 + wv) * 8 + r8];

  const unsigned short* Gp = wg + ((size_t)e * Dn + n0) * Hn;
  const unsigned short* Up = wu + ((size_t)e * Dn + n0) * Hn;

  f32x4 acc[4][4];
#pragma unroll
  for (int i = 0; i < 4; i++)
#pragma unroll
    for (int j = 0; j < 4; j++) acc[i][j] = f32x4{0.f, 0.f, 0.f, 0.f};

  for (int k0 = 0; k0 < Hn; k0 += 64) {
#pragma unroll
    for (int c = 0; c < 8; c++) {
      int ch = c * 4 + wv;
      gload_lds16(xb + (size_t)tokc[c] * Hn + k0 + c8 * 8, (void*)(Xs + ch * 512));
    }
    {  // B: gate chunk (Bs rows wv*8..) and up chunk (Bs rows 32+wv*8..)
      gload_lds16(Gp + (size_t)(wv * 8 + r8) * Hn + k0 + c8 * 8, (void*)(Bs + wv * 512));
      gload_lds16(Up + (size_t)(wv * 8 + r8) * Hn + k0 + c8 * 8, (void*)(Bs + (wv + 4) * 512));
    }
    asm volatile("s_waitcnt vmcnt(0)" ::: "memory");
    __syncthreads();
#pragma unroll
    for (int kk = 0; kk < 2; kk++) {
      bf16_8 a[4], b[4];
#pragma unroll
      for (int i = 0; i < 4; i++)
        a[i] = *reinterpret_cast<const bf16_8*>(Xs + (wv * 64 + i * 16 + fr) * 64 + kk * 32 + kg * 8);
#pragma unroll
      for (int j = 0; j < 4; j++)
        b[j] = *reinterpret_cast<const bf16_8*>(Bs + (j * 16 + fr) * 64 + kk * 32 + kg * 8);
#pragma unroll
      for (int i = 0; i < 4; i++)
#pragma unroll
        for (int j = 0; j < 4; j++)
          acc[i][j] = __builtin_amdgcn_mfma_f32_16x16x32_bf16(a[i], b[j], acc[i][j], 0, 0, 0);
    }
    __syncthreads();
  }

  // ---- epilogue: pair (gate j, up j+2) for same d; activation; store bf16 ----
  const int rg = kg;
  const float* gb = gub + e * 2 * Dn;
  const int d0 = n0 + fr, d1 = n0 + 16 + fr;
  const float gb0 = gb[2 * d0], ub0 = gb[2 * d0 + 1];
  const float gb1 = gb[2 * d1], ub1 = gb[2 * d1 + 1];
#pragma unroll
  for (int i = 0; i < 4; i++) {
#pragma unroll
    for (int r = 0; r < 4; r++) {
      int row = p0 + wv * 64 + i * 16 + rg * 4 + r;
      {
        float g = acc[i][0][r] + gb0;
        float u = acc[i][2][r] + ub0;
        g = fminf(g, kLimit);
        u = fminf(fmaxf(u, -kLimit), kLimit);
        float sg = 1.0f / (1.0f + __expf(-kAlpha * g));
        midc[(size_t)row * Dn + d0] = f2bf((u + 1.0f) * g * sg);
      }
      {
        float g = acc[i][1][r] + gb1;
        float u = acc[i][3][r] + ub1;
        g = fminf(g, kLimit);
        u = fminf(fmaxf(u, -kLimit), kLimit);
        float sg = 1.0f / (1.0f + __expf(-kAlpha * g));
        midc[(size_t)row * Dn + d1] = f2bf((u + 1.0f) * g * sg);
      }
    }
  }
}

// ================= GEMM2: ys[p][h] = midc[p][:] @ Wd_e (bf16 out) =================
// Same shape: BM=256, BN=64, 4 waves (4M x 1N), per-wave 64x64, acc 64 f32.
__launch_bounds__(256, 3)
__global__ void k_gemm2(const unsigned short* __restrict__ midc,
                        const unsigned short* __restrict__ wdt,
                        const int* __restrict__ tileE,
                        const int* __restrict__ tileP0,
                        const int* __restrict__ ntiles,
                        unsigned short* __restrict__ ys) {
  __shared__ __align__(16) unsigned short As[256 * 64];  // 32 KiB
  __shared__ __align__(16) unsigned short Bs[64 * 64];   // 8 KiB
  const int nwg = gridDim.x;  // 640, %8==0
  const int orig = blockIdx.x;
  const int wgid = (orig & 7) * (nwg >> 3) + (orig >> 3);
  const int by = wgid & 15;   // h-panel [0,16)
  const int bx = wgid >> 4;   // M-tile  [0,40)
  if (bx >= *ntiles) return;
  const int e = tileE[bx];
  const int p0 = tileP0[bx];
  const int n0 = by * 64;
  const int tid = threadIdx.x;
  const int wv = tid >> 6, lane = tid & 63;
  const int r8 = lane >> 3, c8 = lane & 7;
  const int fr = lane & 15, kg = lane >> 4;
  const unsigned short* Ap = midc + (size_t)p0 * Dn;
  const unsigned short* Bp = wdt + ((size_t)e * Hn + n0) * Dn;

  f32x4 acc[4][4];
#pragma unroll
  for (int i = 0; i < 4; i++)
#pragma unroll
    for (int j = 0; j < 4; j++) acc[i][j] = f32x4{0.f, 0.f, 0.f, 0.f};

  for (int k0 = 0; k0 < Dn; k0 += 64) {
#pragma unroll
    for (int c = 0; c < 8; c++) {
      int ch = c * 4 + wv;
      gload_lds16(Ap + (size_t)(ch * 8 + r8) * Dn + k0 + c8 * 8, (void*)(As + ch * 512));
    }
#pragma unroll
    for (int c = 0; c < 2; c++) {
      int ch = c * 4 + wv;
      gload_lds16(Bp + (size_t)(ch * 8 + r8) * Dn + k0 + c8 * 8, (void*)(Bs + ch * 512));
    }
    asm volatile("s_waitcnt vmcnt(0)" ::: "memory");
    __syncthreads();
#pragma unroll
    for (int kk = 0; kk < 2; kk++) {
      bf16_8 a[4], b[4];
#pragma unroll
      for (int i = 0; i < 4; i++)
        a[i] = *reinterpret_cast<const bf16_8*>(As + (wv * 64 + i * 16 + fr) * 64 + kk * 32 + kg * 8);
#pragma unroll
      for (int j = 0; j < 4; j++)
        b[j] = *reinterpret_cast<const bf16_8*>(Bs + (j * 16 + fr) * 64 + kk * 32 + kg * 8);
#pragma unroll
      for (int i = 0; i < 4; i++)
#pragma unroll
        for (int j = 0; j < 4; j++)
          acc[i][j] = __builtin_amdgcn_mfma_f32_16x16x32_bf16(a[i], b[j], acc[i][j], 0, 0, 0);
    }
    __syncthreads();
  }

  const int rg = kg;
#pragma unroll
  for (int i = 0; i < 4; i++)
#pragma unroll
    for (int r = 0; r < 4; r++) {
      int row = p0 + wv * 64 + i * 16 + rg * 4 + r;
#pragma unroll
      for (int j = 0; j < 4; j++) {
        int col = n0 + j * 16 + fr;
        ys[(size_t)row * Hn + col] = f2bf(acc[i][j][r]);
      }
    }
}

// ---- combine: out[t][h] = sum_k rw[t,e_k] * (ys[p_k][h] + db[e_k][h]) ----
__global__ void k_combine(const unsigned short* __restrict__ ys, const int* __restrict__ ridx,
                          const float* __restrict__ rw, const int* __restrict__ pos,
                          const float* __restrict__ db, float* __restrict__ out) {
  int idx = blockIdx.x * blockDim.x + threadIdx.x;
  int t = idx >> 7, hc = (idx & 127) << 3;
  int e0 = ridx[2 * t], e1 = ridx[2 * t + 1];
  int p0 = pos[2 * t], p1 = pos[2 * t + 1];
  float w0 = rw[t * En + e0], w1 = rw[t * En + e1];
  uint4 ya = *reinterpret_cast<const uint4*>(ys + (size_t)p0 * Hn + hc);
  uint4 yb = *reinterpret_cast<const uint4*>(ys + (size_t)p1 * Hn + hc);
  float4 da0 = *reinterpret_cast<const float4*>(db + (size_t)e0 * Hn + hc);
  float4 da1 = *reinterpret_cast<const float4*>(db + (size_t)e0 * Hn + hc + 4);
  float4 db0 = *reinterpret_cast<const float4*>(db + (size_t)e1 * Hn + hc);
  float4 db1 = *reinterpret_cast<const float4*>(db + (size_t)e1 * Hn + hc + 4);
  float4 o0, o1;
  o0.x = w0 * (bflo(ya.x) + da0.x) + w1 * (bflo(yb.x) + db0.x);
  o0.y = w0 * (bfhi(ya.x) + da0.y) + w1 * (bfhi(yb.x) + db0.y);
  o0.z = w0 * (bflo(ya.y) + da0.z) + w1 * (bflo(yb.y) + db0.z);
  o0.w = w0 * (bfhi(ya.y) + da0.w) + w1 * (bfhi(yb.y) + db0.w);
  o1.x = w0 * (bflo(ya.z) + da1.x) + w1 * (bflo(yb.z) + db1.x);
  o1.y = w0 * (bfhi(ya.z) + da1.y) + w1 * (bfhi(yb.z) + db1.y);
  o1.z = w0 * (bflo(ya.w) + da1.z) + w1 * (bflo(yb.w) + db1.z);
  o1.w = w0 * (bfhi(ya.w) + da1.w) + w1 * (bfhi(yb.w) + db1.w);
  *reinterpret_cast<float4*>(out + (size_t)t * Hn + hc) = o0;
  *reinterpret_cast<float4*>(out + (size_t)t * Hn + hc + 4) = o1;
}

extern "C" void kernel_launch(void* const* d_in, const int* in_sizes, int n_in,
                              void* d_out, int out_size, void* d_ws, size_t ws_size,
                              hipStream_t stream) {
  (void)in_sizes; (void)n_in; (void)out_size; (void)ws_size;
  const float* hs  = (const float*)d_in[0];
  const int*   ri  = (const int*)d_in[1];
  const float* rw  = (const float*)d_in[2];
  const float* gup = (const float*)d_in[3];
  const float* gub = (const float*)d_in[4];
  const float* dwn = (const float*)d_in[5];
  const float* db  = (const float*)d_in[6];
  float* out = (float*)d_out;

  char* ws = (char*)d_ws;
  int* tix    = (int*)(ws);               // Pmax ints
  int* pos    = (int*)(ws + 65536);       // Sn ints
  int* tileE  = (int*)(ws + 131072);
  int* tileP0 = (int*)(ws + 131584);
  int* ntiles = (int*)(ws + 132096);
  unsigned short* xb   = (unsigned short*)(ws + 262144);                        // 8 MiB
  unsigned short* wg   = (unsigned short*)(ws + 262144 + 8388608);              // 16 MiB
  unsigned short* wu   = (unsigned short*)(ws + 262144 + 8388608 + 16777216);   // 16 MiB
  unsigned short* wdt  = (unsigned short*)(ws + 262144 + 8388608 + 2*16777216); // 16 MiB
  unsigned short* midc = (unsigned short*)(ws + 262144 + 8388608 + 3*16777216); // 20 MiB
  unsigned short* ys   = (unsigned short*)(ws + 262144 + 8388608 + 3*16777216 + (size_t)Pmax * Dn * 2); // 20 MiB

  k_prepass<<<dim3(1 + NB_CVT + NB_TGU), dim3(256), 0, stream>>>(
      hs, ri, gup, xb, wg, wu, tix, pos, tileE, tileP0, ntiles);
  k_main1<<<dim3(NG1 + NB_TDN), dim3(256), 0, stream>>>(
      xb, wg, wu, gub, tix, tileE, tileP0, ntiles, midc, dwn, wdt);
  k_gemm2<<<dim3(MaxT256 * 16), dim3(256), 0, stream>>>(
      midc, wdt, tileE, tileP0, ntiles, ys);
  k_combine<<<dim3(Tn * Hn / 8 / 256), dim3(256), 0, stream>>>(ys, ri, rw, pos, db, out);
}